// Round 1
// baseline (429.231 us; speedup 1.0000x reference)
//
#include <hip/hip_runtime.h>

#define N_NODES 50000
#define N_EDGES 800000
#define F_IN    512
#define H_DIM   256
#define C_DIM   64
#define MPAD    50048   // 391 * 128

typedef __bf16 bf16;
typedef __bf16 bf16x4 __attribute__((ext_vector_type(4)));
typedef __bf16 bf16x8 __attribute__((ext_vector_type(8)));
typedef float  f32x4  __attribute__((ext_vector_type(4)));

__device__ __forceinline__ void gl_lds16(const void* g, void* l) {
    typedef unsigned int u32;
    __builtin_amdgcn_global_load_lds(
        (const __attribute__((address_space(1))) u32*)g,
        (__attribute__((address_space(3))) u32*)l, 16, 0, 0);
}

// ---------------- edge sort (counting sort by destination row) ----------------

__global__ __launch_bounds__(256) void hist_k(const int* __restrict__ rows,
                                              int* __restrict__ cnt) {
    int e = blockIdx.x * 256 + threadIdx.x;
    atomicAdd(&cnt[rows[e]], 1);
}

__global__ __launch_bounds__(1024) void scan_k(const int* __restrict__ cnt,
                                               int* __restrict__ starts,
                                               int* __restrict__ cursor) {
    __shared__ int buf[1024];
    int tid = threadIdx.x;
    int running = 0;
    for (int base = 0; base < N_NODES; base += 1024) {
        int i = base + tid;
        int v = (i < N_NODES) ? cnt[i] : 0;
        buf[tid] = v;
        __syncthreads();
        for (int off = 1; off < 1024; off <<= 1) {
            int t = (tid >= off) ? buf[tid - off] : 0;
            __syncthreads();
            buf[tid] += t;
            __syncthreads();
        }
        int excl = running + buf[tid] - v;
        if (i < N_NODES) { starts[i] = excl; cursor[i] = excl; }
        running += buf[1023];
        __syncthreads();
    }
    if (tid == 0) starts[N_NODES] = N_EDGES;
}

__global__ __launch_bounds__(256) void scatter_k(const int* __restrict__ rows,
                                                 const int* __restrict__ cols,
                                                 const float* __restrict__ vals,
                                                 int* __restrict__ cursor,
                                                 int* __restrict__ ecol,
                                                 float* __restrict__ eval) {
    int e = blockIdx.x * 256 + threadIdx.x;
    int r = rows[e];
    int p = atomicAdd(&cursor[r], 1);
    ecol[p] = cols[e];
    eval[p] = vals[e];
}

// ---------------- dtype prep ----------------

__global__ __launch_bounds__(256) void cvt_nf_k(const float* __restrict__ nf,
                                                bf16* __restrict__ a16) {
    size_t gid = (size_t)blockIdx.x * 256 + threadIdx.x;   // 3.2M threads, 8 elems each
    const f32x4* s = (const f32x4*)nf;
    f32x4 u = s[gid * 2], v = s[gid * 2 + 1];
    bf16x8 o;
    o[0] = (bf16)u[0]; o[1] = (bf16)u[1]; o[2] = (bf16)u[2]; o[3] = (bf16)u[3];
    o[4] = (bf16)v[0]; o[5] = (bf16)v[1]; o[6] = (bf16)v[2]; o[7] = (bf16)v[3];
    *(bf16x8*)(a16 + gid * 8) = o;
}

__global__ __launch_bounds__(256) void tr_w1_k(const float* __restrict__ W,
                                               bf16* __restrict__ Wt) {
    int i = blockIdx.x * 256 + threadIdx.x;   // 512*256 elems
    int k = i >> 8, n = i & 255;
    Wt[n * F_IN + k] = (bf16)W[i];
}

__global__ __launch_bounds__(256) void tr_w2_k(const float* __restrict__ W,
                                               bf16* __restrict__ Wt) {
    int i = blockIdx.x * 256 + threadIdx.x;   // 256*64 elems
    int k = i >> 6, n = i & 63;
    Wt[n * H_DIM + k] = (bf16)W[i];
}

// ---------------- bf16 MFMA GEMM: C[M,N] = A[M,K] @ Bt[N,K]^T + bias ----------------
// 128-row tile, BK=64, 4 waves (2x2), global_load_lds staging, single-buffer LDS.

template <int BN, bool BF16OUT>
__global__ __launch_bounds__(256) void gemm_k(const bf16* __restrict__ A,
                                              const bf16* __restrict__ Bt,
                                              const float* __restrict__ bias,
                                              void* __restrict__ C,
                                              int M, int K, int Nc) {
    constexpr int BM = 128, BK = 64;
    constexpr int NFRAG = BN / 32;               // frags per wave in N
    constexpr int A_ISS = (BM * BK * 2) / 4096;  // 4
    constexpr int B_ISS = (BN * BK * 2) / 4096;  // 4 (BN=128) or 2 (BN=64)
    __shared__ bf16 As[BM * BK];
    __shared__ bf16 Bs[BN * BK];

    int tid = threadIdx.x;
    int wid = tid >> 6, lane = tid & 63;
    int wr = wid >> 1, wc = wid & 1;
    int bm = blockIdx.x, bn = blockIdx.y;

    f32x4 acc[4][NFRAG];
#pragma unroll
    for (int m = 0; m < 4; m++)
#pragma unroll
        for (int n = 0; n < NFRAG; n++) acc[m][n] = (f32x4){0.f, 0.f, 0.f, 0.f};

    for (int kt = 0; kt < K; kt += BK) {
#pragma unroll
        for (int j = 0; j < A_ISS; j++) {
            int chunk = j * 256 + tid;       // 16B chunks; 8 per 64-elem row
            int row = chunk >> 3, kc = chunk & 7;
            gl_lds16(A + (size_t)(bm * BM + row) * K + kt + kc * 8,
                     &As[(j * 256 + wid * 64) * 8]);
        }
#pragma unroll
        for (int j = 0; j < B_ISS; j++) {
            int chunk = j * 256 + tid;
            int row = chunk >> 3, kc = chunk & 7;
            gl_lds16(Bt + (size_t)(bn * BN + row) * K + kt + kc * 8,
                     &Bs[(j * 256 + wid * 64) * 8]);
        }
        __syncthreads();

        bf16x8 afr[2][4], bfr[2][NFRAG];
#pragma unroll
        for (int kk = 0; kk < 2; kk++) {
#pragma unroll
            for (int m = 0; m < 4; m++)
                afr[kk][m] = *(const bf16x8*)&As[(wr * 64 + m * 16 + (lane & 15)) * BK +
                                                 kk * 32 + (lane >> 4) * 8];
#pragma unroll
            for (int n = 0; n < NFRAG; n++)
                bfr[kk][n] = *(const bf16x8*)&Bs[(wc * (BN / 2) + n * 16 + (lane & 15)) * BK +
                                                 kk * 32 + (lane >> 4) * 8];
        }
#pragma unroll
        for (int kk = 0; kk < 2; kk++)
#pragma unroll
            for (int m = 0; m < 4; m++)
#pragma unroll
                for (int n = 0; n < NFRAG; n++)
                    acc[m][n] = __builtin_amdgcn_mfma_f32_16x16x32_bf16(
                        afr[kk][m], bfr[kk][n], acc[m][n], 0, 0, 0);
        __syncthreads();
    }

    // epilogue: C/D layout col=lane&15, row=(lane>>4)*4+r  [verified layout]
#pragma unroll
    for (int m = 0; m < 4; m++) {
        int row0 = bm * BM + wr * 64 + m * 16 + (lane >> 4) * 4;
#pragma unroll
        for (int n = 0; n < NFRAG; n++) {
            int col = bn * BN + wc * (BN / 2) + n * 16 + (lane & 15);
            float bz = bias[col];
#pragma unroll
            for (int r = 0; r < 4; r++) {
                int row = row0 + r;
                if (row < M) {
                    float v = acc[m][n][r] + bz;
                    if constexpr (BF16OUT)
                        ((bf16*)C)[(size_t)row * Nc + col] = (bf16)v;
                    else
                        ((float*)C)[(size_t)row * Nc + col] = v;
                }
            }
        }
    }
}

// ---------------- SpMM1: x[i,:] = relu(sum vals * support1[col,:]), D=256, bf16 ----------------

__global__ __launch_bounds__(256) void spmm1_k(const int* __restrict__ starts,
                                               const int* __restrict__ ecol,
                                               const float* __restrict__ eval,
                                               const bf16* __restrict__ s1,
                                               bf16* __restrict__ x16) {
    int wid = threadIdx.x >> 6, lane = threadIdx.x & 63;
    int row = blockIdx.x * 4 + wid;
    if (row >= N_NODES) return;
    int s = starts[row], e = starts[row + 1];
    float a0 = 0.f, a1 = 0.f, a2 = 0.f, a3 = 0.f;
    for (int p = s; p < e; ++p) {
        int c = ecol[p];
        float v = eval[p];
        bf16x4 g = *(const bf16x4*)(s1 + (size_t)c * H_DIM + lane * 4);
        a0 += v * (float)g[0];
        a1 += v * (float)g[1];
        a2 += v * (float)g[2];
        a3 += v * (float)g[3];
    }
    bf16x4 o;
    o[0] = (bf16)fmaxf(a0, 0.f);
    o[1] = (bf16)fmaxf(a1, 0.f);
    o[2] = (bf16)fmaxf(a2, 0.f);
    o[3] = (bf16)fmaxf(a3, 0.f);
    *(bf16x4*)(x16 + (size_t)row * H_DIM + lane * 4) = o;
}

// ---------------- SpMM2 + log_softmax fused: D=64, lane = class ----------------

__global__ __launch_bounds__(256) void spmm2_sm_k(const int* __restrict__ starts,
                                                  const int* __restrict__ ecol,
                                                  const float* __restrict__ eval,
                                                  const float* __restrict__ s2,
                                                  float* __restrict__ out) {
    int wid = threadIdx.x >> 6, lane = threadIdx.x & 63;
    int row = blockIdx.x * 4 + wid;
    if (row >= N_NODES) return;
    int s = starts[row], e = starts[row + 1];
    float acc = 0.f;
    for (int p = s; p < e; ++p)
        acc += eval[p] * s2[(size_t)ecol[p] * C_DIM + lane];
    float mx = acc;
#pragma unroll
    for (int off = 32; off >= 1; off >>= 1) mx = fmaxf(mx, __shfl_xor(mx, off, 64));
    float ex = expf(acc - mx);
    float se = ex;
#pragma unroll
    for (int off = 32; off >= 1; off >>= 1) se += __shfl_xor(se, off, 64);
    out[(size_t)row * C_DIM + lane] = (acc - mx) - logf(se);
}

// ---------------- launch ----------------

extern "C" void kernel_launch(void* const* d_in, const int* in_sizes, int n_in,
                              void* d_out, int out_size, void* d_ws, size_t ws_size,
                              hipStream_t stream) {
    const float* nf   = (const float*)d_in[0];
    const int*   rows = (const int*)d_in[1];
    const int*   cols = (const int*)d_in[2];
    const float* vals = (const float*)d_in[3];
    const float* W1   = (const float*)d_in[4];
    const float* b1   = (const float*)d_in[5];
    const float* W2   = (const float*)d_in[6];
    const float* b2   = (const float*)d_in[7];
    float* out = (float*)d_out;

    char* w = (char*)d_ws;
    auto alloc = [&](size_t b) { void* p = (void*)w; w += (b + 255) & ~(size_t)255; return p; };

    // region 0: A_bf16 [MPAD][512], later reused as x_bf16 [MPAD][256]
    bf16* A16 = (bf16*)alloc((size_t)MPAD * F_IN * 2);
    bf16* x16 = A16;
    // region 1: support1 bf16 [N][256], later reused as support2 f32 [N][64]
    bf16*  sup1 = (bf16*)alloc((size_t)N_NODES * H_DIM * 2);
    float* sup2 = (float*)sup1;
    bf16* W1t = (bf16*)alloc((size_t)H_DIM * F_IN * 2);
    bf16* W2t = (bf16*)alloc((size_t)C_DIM * H_DIM * 2);
    int* cnt    = (int*)alloc((size_t)N_NODES * 4);
    int* starts = (int*)alloc((size_t)(N_NODES + 1) * 4);
    int* cursor = (int*)alloc((size_t)N_NODES * 4);
    int*   ecol = (int*)alloc((size_t)N_EDGES * 4);
    float* eval = (float*)alloc((size_t)N_EDGES * 4);

    // edge sort
    hipMemsetAsync(cnt, 0, (size_t)N_NODES * 4, stream);
    hist_k<<<N_EDGES / 256, 256, 0, stream>>>(rows, cnt);
    scan_k<<<1, 1024, 0, stream>>>(cnt, starts, cursor);
    scatter_k<<<N_EDGES / 256, 256, 0, stream>>>(rows, cols, vals, cursor, ecol, eval);

    // dtype prep
    cvt_nf_k<<<(N_NODES * F_IN / 8) / 256, 256, 0, stream>>>(nf, A16);
    tr_w1_k<<<(F_IN * H_DIM) / 256, 256, 0, stream>>>(W1, W1t);
    tr_w2_k<<<(H_DIM * C_DIM) / 256, 256, 0, stream>>>(W2, W2t);

    // layer 1
    gemm_k<128, true><<<dim3(MPAD / 128, H_DIM / 128), 256, 0, stream>>>(
        A16, W1t, b1, (void*)sup1, N_NODES, F_IN, H_DIM);
    spmm1_k<<<(N_NODES + 3) / 4, 256, 0, stream>>>(starts, ecol, eval, sup1, x16);

    // layer 2 + softmax
    gemm_k<64, false><<<dim3(MPAD / 128, 1), 256, 0, stream>>>(
        x16, W2t, b2, (void*)sup2, N_NODES, H_DIM, C_DIM);
    spmm2_sm_k<<<(N_NODES + 3) / 4, 256, 0, stream>>>(starts, ecol, eval, sup2, out);

    (void)in_sizes; (void)n_in; (void)out_size; (void)ws_size;
}

// Round 2
// 278.009 us; speedup vs baseline: 1.5439x; 1.5439x over previous
//
#include <hip/hip_runtime.h>

#define N_NODES 50000
#define N_EDGES 800000
#define F_IN    512
#define H_DIM   256
#define C_DIM   64
#define MPAD    50048   // 391 * 128

typedef __bf16 bf16;
typedef __bf16 bf16x4 __attribute__((ext_vector_type(4)));
typedef __bf16 bf16x8 __attribute__((ext_vector_type(8)));
typedef float  f32x4  __attribute__((ext_vector_type(4)));
typedef int    i32x4  __attribute__((ext_vector_type(4)));

__device__ __forceinline__ void gl_lds16(const void* g, void* l) {
    typedef unsigned int u32;
    __builtin_amdgcn_global_load_lds(
        (const __attribute__((address_space(1))) u32*)g,
        (__attribute__((address_space(3))) u32*)l, 16, 0, 0);
}

// ---------------- edge sort (counting sort by destination row) ----------------

__global__ __launch_bounds__(256) void hist_k(const int* __restrict__ rows,
                                              int* __restrict__ cnt) {
    int e = blockIdx.x * 256 + threadIdx.x;
    atomicAdd(&cnt[rows[e]], 1);
}

// multi-block scan: 49 blocks x 256 threads, 4 elems/thread (1024/block)
__global__ __launch_bounds__(256) void scan1_k(const int* __restrict__ cnt,
                                               int* __restrict__ starts,
                                               int* __restrict__ bsum) {
    __shared__ int wtot[4];
    int tid = threadIdx.x, wid = tid >> 6, lane = tid & 63;
    int base = blockIdx.x * 1024 + tid * 4;
    i32x4 v = (i32x4){0, 0, 0, 0};
    if (base < N_NODES) v = *(const i32x4*)(cnt + base);
    int t = v[0] + v[1] + v[2] + v[3];
    int incl = t;
#pragma unroll
    for (int off = 1; off < 64; off <<= 1) {
        int u = __shfl_up(incl, off, 64);
        if (lane >= off) incl += u;
    }
    if (lane == 63) wtot[wid] = incl;
    __syncthreads();
    int wpre = 0;
#pragma unroll
    for (int w = 0; w < 4; w++)
        if (w < wid) wpre += wtot[w];
    int excl = wpre + incl - t;
    if (base < N_NODES) {
        i32x4 o;
        o[0] = excl;
        o[1] = excl + v[0];
        o[2] = excl + v[0] + v[1];
        o[3] = excl + v[0] + v[1] + v[2];
        *(i32x4*)(starts + base) = o;
    }
    if (tid == 255) bsum[blockIdx.x] = wpre + incl;
}

__global__ __launch_bounds__(64) void scan2_k(int* __restrict__ bsum,
                                              int* __restrict__ boff) {
    int lane = threadIdx.x;
    int v = (lane < 49) ? bsum[lane] : 0;
    int incl = v;
#pragma unroll
    for (int off = 1; off < 64; off <<= 1) {
        int u = __shfl_up(incl, off, 64);
        if (lane >= off) incl += u;
    }
    if (lane < 49) boff[lane] = incl - v;
}

__global__ __launch_bounds__(256) void scan3_k(int* __restrict__ starts,
                                               const int* __restrict__ boff,
                                               int* __restrict__ cursor) {
    int i = blockIdx.x * 1024 + threadIdx.x * 4;
    int off = boff[blockIdx.x];
    if (i < N_NODES) {
        i32x4 s = *(const i32x4*)(starts + i);
        s[0] += off; s[1] += off; s[2] += off; s[3] += off;
        *(i32x4*)(starts + i) = s;
        *(i32x4*)(cursor + i) = s;
    }
    if (blockIdx.x == 0 && threadIdx.x == 0) starts[N_NODES] = N_EDGES;
}

__global__ __launch_bounds__(256) void scatter_k(const int* __restrict__ rows,
                                                 const int* __restrict__ cols,
                                                 const float* __restrict__ vals,
                                                 int* __restrict__ cursor,
                                                 int* __restrict__ ecol,
                                                 float* __restrict__ eval) {
    int e = blockIdx.x * 256 + threadIdx.x;
    int r = rows[e];
    int p = atomicAdd(&cursor[r], 1);
    ecol[p] = cols[e];
    eval[p] = vals[e];
}

// ---------------- dtype prep ----------------

__global__ __launch_bounds__(256) void cvt_nf_k(const float* __restrict__ nf,
                                                bf16* __restrict__ a16) {
    size_t gid = (size_t)blockIdx.x * 256 + threadIdx.x;
    const f32x4* s = (const f32x4*)nf;
    f32x4 u = s[gid * 2], v = s[gid * 2 + 1];
    bf16x8 o;
    o[0] = (bf16)u[0]; o[1] = (bf16)u[1]; o[2] = (bf16)u[2]; o[3] = (bf16)u[3];
    o[4] = (bf16)v[0]; o[5] = (bf16)v[1]; o[6] = (bf16)v[2]; o[7] = (bf16)v[3];
    *(bf16x8*)(a16 + gid * 8) = o;
}

__global__ __launch_bounds__(256) void tr_w1_k(const float* __restrict__ W,
                                               bf16* __restrict__ Wt) {
    int i = blockIdx.x * 256 + threadIdx.x;
    int k = i >> 8, n = i & 255;
    Wt[n * F_IN + k] = (bf16)W[i];
}

__global__ __launch_bounds__(256) void tr_w2_k(const float* __restrict__ W,
                                               bf16* __restrict__ Wt) {
    int i = blockIdx.x * 256 + threadIdx.x;
    int k = i >> 6, n = i & 63;
    Wt[n * H_DIM + k] = (bf16)W[i];
}

// ---------------- bf16 MFMA GEMM: C[M,N] = A[M,K] @ Bt[N,K]^T + bias ----------------

template <int BN, bool BF16OUT>
__global__ __launch_bounds__(256) void gemm_k(const bf16* __restrict__ A,
                                              const bf16* __restrict__ Bt,
                                              const float* __restrict__ bias,
                                              void* __restrict__ C,
                                              int M, int K, int Nc) {
    constexpr int BM = 128, BK = 64;
    constexpr int NFRAG = BN / 32;
    constexpr int A_ISS = (BM * BK * 2) / 4096;
    constexpr int B_ISS = (BN * BK * 2) / 4096;
    __shared__ bf16 As[BM * BK];
    __shared__ bf16 Bs[BN * BK];

    int tid = threadIdx.x;
    int wid = tid >> 6, lane = tid & 63;
    int wr = wid >> 1, wc = wid & 1;
    int bm = blockIdx.x, bn = blockIdx.y;

    f32x4 acc[4][NFRAG];
#pragma unroll
    for (int m = 0; m < 4; m++)
#pragma unroll
        for (int n = 0; n < NFRAG; n++) acc[m][n] = (f32x4){0.f, 0.f, 0.f, 0.f};

    for (int kt = 0; kt < K; kt += BK) {
#pragma unroll
        for (int j = 0; j < A_ISS; j++) {
            int chunk = j * 256 + tid;
            int row = chunk >> 3, kc = chunk & 7;
            gl_lds16(A + (size_t)(bm * BM + row) * K + kt + kc * 8,
                     &As[(j * 256 + wid * 64) * 8]);
        }
#pragma unroll
        for (int j = 0; j < B_ISS; j++) {
            int chunk = j * 256 + tid;
            int row = chunk >> 3, kc = chunk & 7;
            gl_lds16(Bt + (size_t)(bn * BN + row) * K + kt + kc * 8,
                     &Bs[(j * 256 + wid * 64) * 8]);
        }
        __syncthreads();

        bf16x8 afr[2][4], bfr[2][NFRAG];
#pragma unroll
        for (int kk = 0; kk < 2; kk++) {
#pragma unroll
            for (int m = 0; m < 4; m++)
                afr[kk][m] = *(const bf16x8*)&As[(wr * 64 + m * 16 + (lane & 15)) * BK +
                                                 kk * 32 + (lane >> 4) * 8];
#pragma unroll
            for (int n = 0; n < NFRAG; n++)
                bfr[kk][n] = *(const bf16x8*)&Bs[(wc * (BN / 2) + n * 16 + (lane & 15)) * BK +
                                                 kk * 32 + (lane >> 4) * 8];
        }
#pragma unroll
        for (int kk = 0; kk < 2; kk++)
#pragma unroll
            for (int m = 0; m < 4; m++)
#pragma unroll
                for (int n = 0; n < NFRAG; n++)
                    acc[m][n] = __builtin_amdgcn_mfma_f32_16x16x32_bf16(
                        afr[kk][m], bfr[kk][n], acc[m][n], 0, 0, 0);
        __syncthreads();
    }

#pragma unroll
    for (int m = 0; m < 4; m++) {
        int row0 = bm * BM + wr * 64 + m * 16 + (lane >> 4) * 4;
#pragma unroll
        for (int n = 0; n < NFRAG; n++) {
            int col = bn * BN + wc * (BN / 2) + n * 16 + (lane & 15);
            float bz = bias[col];
#pragma unroll
            for (int r = 0; r < 4; r++) {
                int row = row0 + r;
                if (row < M) {
                    float v = acc[m][n][r] + bz;
                    if constexpr (BF16OUT)
                        ((bf16*)C)[(size_t)row * Nc + col] = (bf16)v;
                    else
                        ((float*)C)[(size_t)row * Nc + col] = v;
                }
            }
        }
    }
}

// ---------------- SpMM1: x[i,:] = relu(sum vals * s1[col,:]), D=256, bf16, unroll 4 ----------------

__global__ __launch_bounds__(256) void spmm1_k(const int* __restrict__ starts,
                                               const int* __restrict__ ecol,
                                               const float* __restrict__ eval,
                                               const bf16* __restrict__ s1,
                                               bf16* __restrict__ x16) {
    int wid = threadIdx.x >> 6, lane = threadIdx.x & 63;
    int row = blockIdx.x * 4 + wid;
    if (row >= N_NODES) return;
    int s = starts[row], e = starts[row + 1];
    f32x4 acc = (f32x4){0.f, 0.f, 0.f, 0.f};
    int p = s;
    for (; p + 4 <= e; p += 4) {
        int c0 = ecol[p], c1 = ecol[p + 1], c2 = ecol[p + 2], c3 = ecol[p + 3];
        float v0 = eval[p], v1 = eval[p + 1], v2 = eval[p + 2], v3 = eval[p + 3];
        bf16x4 g0 = *(const bf16x4*)(s1 + (size_t)c0 * H_DIM + lane * 4);
        bf16x4 g1 = *(const bf16x4*)(s1 + (size_t)c1 * H_DIM + lane * 4);
        bf16x4 g2 = *(const bf16x4*)(s1 + (size_t)c2 * H_DIM + lane * 4);
        bf16x4 g3 = *(const bf16x4*)(s1 + (size_t)c3 * H_DIM + lane * 4);
#pragma unroll
        for (int j = 0; j < 4; j++)
            acc[j] += v0 * (float)g0[j] + v1 * (float)g1[j] +
                      v2 * (float)g2[j] + v3 * (float)g3[j];
    }
    for (; p < e; ++p) {
        int c = ecol[p];
        float v = eval[p];
        bf16x4 g = *(const bf16x4*)(s1 + (size_t)c * H_DIM + lane * 4);
#pragma unroll
        for (int j = 0; j < 4; j++) acc[j] += v * (float)g[j];
    }
    bf16x4 o;
#pragma unroll
    for (int j = 0; j < 4; j++) o[j] = (bf16)fmaxf(acc[j], 0.f);
    *(bf16x4*)(x16 + (size_t)row * H_DIM + lane * 4) = o;
}

// ---------------- SpMM2 + log_softmax fused: D=64, lane = class, unroll 4 ----------------

__global__ __launch_bounds__(256) void spmm2_sm_k(const int* __restrict__ starts,
                                                  const int* __restrict__ ecol,
                                                  const float* __restrict__ eval,
                                                  const float* __restrict__ s2,
                                                  float* __restrict__ out) {
    int wid = threadIdx.x >> 6, lane = threadIdx.x & 63;
    int row = blockIdx.x * 4 + wid;
    if (row >= N_NODES) return;
    int s = starts[row], e = starts[row + 1];
    float acc = 0.f;
    int p = s;
    for (; p + 4 <= e; p += 4) {
        int c0 = ecol[p], c1 = ecol[p + 1], c2 = ecol[p + 2], c3 = ecol[p + 3];
        float v0 = eval[p], v1 = eval[p + 1], v2 = eval[p + 2], v3 = eval[p + 3];
        float g0 = s2[(size_t)c0 * C_DIM + lane];
        float g1 = s2[(size_t)c1 * C_DIM + lane];
        float g2 = s2[(size_t)c2 * C_DIM + lane];
        float g3 = s2[(size_t)c3 * C_DIM + lane];
        acc += v0 * g0 + v1 * g1 + v2 * g2 + v3 * g3;
    }
    for (; p < e; ++p)
        acc += eval[p] * s2[(size_t)ecol[p] * C_DIM + lane];
    float mx = acc;
#pragma unroll
    for (int off = 32; off >= 1; off >>= 1) mx = fmaxf(mx, __shfl_xor(mx, off, 64));
    float ex = expf(acc - mx);
    float se = ex;
#pragma unroll
    for (int off = 32; off >= 1; off >>= 1) se += __shfl_xor(se, off, 64);
    out[(size_t)row * C_DIM + lane] = (acc - mx) - logf(se);
}

// ---------------- launch ----------------

extern "C" void kernel_launch(void* const* d_in, const int* in_sizes, int n_in,
                              void* d_out, int out_size, void* d_ws, size_t ws_size,
                              hipStream_t stream) {
    const float* nf   = (const float*)d_in[0];
    const int*   rows = (const int*)d_in[1];
    const int*   cols = (const int*)d_in[2];
    const float* vals = (const float*)d_in[3];
    const float* W1   = (const float*)d_in[4];
    const float* b1   = (const float*)d_in[5];
    const float* W2   = (const float*)d_in[6];
    const float* b2   = (const float*)d_in[7];
    float* out = (float*)d_out;

    char* w = (char*)d_ws;
    auto alloc = [&](size_t b) { void* p = (void*)w; w += (b + 255) & ~(size_t)255; return p; };

    bf16* A16 = (bf16*)alloc((size_t)MPAD * F_IN * 2);
    bf16* x16 = A16;
    bf16*  sup1 = (bf16*)alloc((size_t)N_NODES * H_DIM * 2);
    float* sup2 = (float*)sup1;
    bf16* W1t = (bf16*)alloc((size_t)H_DIM * F_IN * 2);
    bf16* W2t = (bf16*)alloc((size_t)C_DIM * H_DIM * 2);
    int* cnt    = (int*)alloc((size_t)N_NODES * 4);
    int* starts = (int*)alloc((size_t)(N_NODES + 1) * 4);
    int* cursor = (int*)alloc((size_t)N_NODES * 4);
    int* bsum   = (int*)alloc(64 * 4);
    int* boff   = (int*)alloc(64 * 4);
    int*   ecol = (int*)alloc((size_t)N_EDGES * 4);
    float* eval = (float*)alloc((size_t)N_EDGES * 4);

    // edge sort
    hipMemsetAsync(cnt, 0, (size_t)N_NODES * 4, stream);
    hist_k<<<N_EDGES / 256, 256, 0, stream>>>(rows, cnt);
    scan1_k<<<49, 256, 0, stream>>>(cnt, starts, bsum);
    scan2_k<<<1, 64, 0, stream>>>(bsum, boff);
    scan3_k<<<49, 256, 0, stream>>>(starts, boff, cursor);
    scatter_k<<<N_EDGES / 256, 256, 0, stream>>>(rows, cols, vals, cursor, ecol, eval);

    // dtype prep
    cvt_nf_k<<<(N_NODES * F_IN / 8) / 256, 256, 0, stream>>>(nf, A16);
    tr_w1_k<<<(F_IN * H_DIM) / 256, 256, 0, stream>>>(W1, W1t);
    tr_w2_k<<<(H_DIM * C_DIM) / 256, 256, 0, stream>>>(W2, W2t);

    // layer 1
    gemm_k<128, true><<<dim3(MPAD / 128, H_DIM / 128), 256, 0, stream>>>(
        A16, W1t, b1, (void*)sup1, N_NODES, F_IN, H_DIM);
    spmm1_k<<<(N_NODES + 3) / 4, 256, 0, stream>>>(starts, ecol, eval, sup1, x16);

    // layer 2 + softmax
    gemm_k<64, false><<<dim3(MPAD / 128, 1), 256, 0, stream>>>(
        x16, W2t, b2, (void*)sup2, N_NODES, H_DIM, C_DIM);
    spmm2_sm_k<<<(N_NODES + 3) / 4, 256, 0, stream>>>(starts, ecol, eval, sup2, out);

    (void)in_sizes; (void)n_in; (void)out_size; (void)ws_size;
}